// Round 7
// baseline (529.958 us; speedup 1.0000x reference)
//
#include <hip/hip_runtime.h>
#include <hip/hip_fp16.h>
#include <cstdint>

// ---------------------------------------------------------------------------
// 3-layer GAT (PyG GATConv semantics) on MI355X.
//   CSR by dst (histogram -> 3-phase scan -> atomic scatter, esrc+edst)
//   per layer: fp32 GEMM + fused-alpha epilogue (fp16 feature out)
//              -> lane-parallel edge-weight pass (w = exp(lrelu(.)), no
//                 max-shift: logits ~N(0,2), fp32 exp cannot overflow)
//              -> aggregate: block per dst, wave=head, 4 groups x 16 lanes;
//                 inner loop = w load + uint2 fp16 gather + fma only.
// ---------------------------------------------------------------------------

__global__ __launch_bounds__(256) void count_kernel(const int* __restrict__ ei,
                                                    int E, int N,
                                                    int* __restrict__ deg) {
  int g = blockIdx.x * 256 + threadIdx.x;
  if (g >= E + N) return;
  int dst = (g < E) ? ei[E + g] : (g - E);  // self-loop tail
  atomicAdd(&deg[dst], 1);
}

__global__ __launch_bounds__(256) void deg_block_reduce(const int* __restrict__ deg,
                                                        int* __restrict__ bsum, int N) {
  __shared__ int red[4];
  int b = blockIdx.x;
  int v = 0;
#pragma unroll
  for (int s = 0; s < 4; ++s) {
    int idx = b * 1024 + s * 256 + threadIdx.x;
    if (idx < N) v += deg[idx];
  }
  for (int off = 32; off; off >>= 1) v += __shfl_down(v, off);
  if ((threadIdx.x & 63) == 0) red[threadIdx.x >> 6] = v;
  __syncthreads();
  if (threadIdx.x == 0) bsum[b] = red[0] + red[1] + red[2] + red[3];
}

__global__ __launch_bounds__(1024) void small_scan(const int* __restrict__ bsum,
                                                   int* __restrict__ bpre, int NB) {
  __shared__ int buf[1024];
  int v = (threadIdx.x < NB) ? bsum[threadIdx.x] : 0;
  buf[threadIdx.x] = v;
  __syncthreads();
  for (int off = 1; off < 1024; off <<= 1) {
    int tv = (threadIdx.x >= off) ? buf[threadIdx.x - off] : 0;
    __syncthreads();
    buf[threadIdx.x] += tv;
    __syncthreads();
  }
  if (threadIdx.x < NB) bpre[threadIdx.x] = buf[threadIdx.x] - v;
}

__global__ __launch_bounds__(1024) void scan_final(const int* __restrict__ deg,
                                                   const int* __restrict__ bpre,
                                                   int* __restrict__ row_off,
                                                   int* __restrict__ cursor,
                                                   int N, int total) {
  __shared__ int buf[1024];
  int b = blockIdx.x;
  int i = b * 1024 + threadIdx.x;
  int v = (i < N) ? deg[i] : 0;
  buf[threadIdx.x] = v;
  __syncthreads();
  for (int off = 1; off < 1024; off <<= 1) {
    int tv = (threadIdx.x >= off) ? buf[threadIdx.x - off] : 0;
    __syncthreads();
    buf[threadIdx.x] += tv;
    __syncthreads();
  }
  if (i < N) {
    int ro = bpre[b] + buf[threadIdx.x] - v;  // exclusive
    row_off[i] = ro;
    cursor[i] = ro;
  }
  if (i == 0) row_off[N] = total;
}

__global__ __launch_bounds__(256) void scatter_kernel(const int* __restrict__ ei,
                                                      int E, int N,
                                                      int* __restrict__ cursor,
                                                      int* __restrict__ esrc,
                                                      int* __restrict__ edst) {
  int g = blockIdx.x * 256 + threadIdx.x;
  if (g >= E + N) return;
  int src, dst;
  if (g < E) { src = ei[g]; dst = ei[E + g]; }
  else       { src = g - E; dst = src; }
  int pos = atomicAdd(&cursor[dst], 1);
  esrc[pos] = src;
  edst[pos] = dst;
}

// fp32 GEMM  T = A@B  with fused alpha epilogue; T written as fp16.
// BM=128 x BN tile, 256 thr, per-thread 8 x (BN/16). K-step 16.
template <int BN>
__global__ __launch_bounds__(256) void gemm_alpha(
    const float* __restrict__ A, const float* __restrict__ B,
    __half* __restrict__ Tout,
    const float* __restrict__ avec_src, const float* __restrict__ avec_dst,
    float* __restrict__ asrc, float* __restrict__ adst,
    int M, int K, int Ncol) {
  constexpr int TN = BN / 16;
  __shared__ float As[16][132];
  __shared__ float Bs[16][BN + 4];
  int tid = threadIdx.x;
  int row0 = blockIdx.x * 128, col0 = blockIdx.y * BN;
  int ty = tid >> 4, tx = tid & 15;
  int ar = tid >> 1, ak = (tid & 1) << 3;
  int arow = min(row0 + ar, M - 1);
  float acc[8][TN] = {};
  for (int kk = 0; kk < K; kk += 16) {
    const float* Ap = A + (size_t)arow * K + kk + ak;
    float4 a0 = *reinterpret_cast<const float4*>(Ap);
    float4 a1 = *reinterpret_cast<const float4*>(Ap + 4);
    As[ak + 0][ar] = a0.x; As[ak + 1][ar] = a0.y;
    As[ak + 2][ar] = a0.z; As[ak + 3][ar] = a0.w;
    As[ak + 4][ar] = a1.x; As[ak + 5][ar] = a1.y;
    As[ak + 6][ar] = a1.z; As[ak + 7][ar] = a1.w;
    if (BN == 128) {
#pragma unroll
      for (int q = 0; q < 2; ++q) {
        int lin = tid + q * 256;
        int brow = lin >> 5, bc4 = (lin & 31) << 2;
        *reinterpret_cast<float4*>(&Bs[brow][bc4]) =
            *reinterpret_cast<const float4*>(B + (size_t)(kk + brow) * Ncol + col0 + bc4);
      }
    } else {
      int brow = tid >> 4, bc4 = (tid & 15) << 2;
      *reinterpret_cast<float4*>(&Bs[brow][bc4]) =
          *reinterpret_cast<const float4*>(B + (size_t)(kk + brow) * Ncol + col0 + bc4);
    }
    __syncthreads();
#pragma unroll
    for (int k = 0; k < 16; ++k) {
      float a[8], bv[TN];
      *reinterpret_cast<float4*>(&a[0]) = *reinterpret_cast<const float4*>(&As[k][ty * 8]);
      *reinterpret_cast<float4*>(&a[4]) = *reinterpret_cast<const float4*>(&As[k][ty * 8 + 4]);
#pragma unroll
      for (int q = 0; q < TN / 4; ++q)
        *reinterpret_cast<float4*>(&bv[q * 4]) =
            *reinterpret_cast<const float4*>(&Bs[k][tx * TN + q * 4]);
#pragma unroll
      for (int i = 0; i < 8; ++i)
#pragma unroll
        for (int jn = 0; jn < TN; ++jn)
          acc[i][jn] = fmaf(a[i], bv[jn], acc[i][jn]);
    }
    __syncthreads();
  }

  // ---- fused alpha dots (fp32 exact) ----
  int H = Ncol >> 6;
  int head, seg;
  if (BN == 128) { head = (col0 >> 6) + (tx >> 3); seg = (tx & 7) * 8; }
  else           { head = 0;                        seg = tx * 4; }
  float avs[TN], avd[TN];
#pragma unroll
  for (int j = 0; j < TN; ++j) {
    avs[j] = avec_src[head * 64 + seg + j];
    avd[j] = avec_dst[head * 64 + seg + j];
  }

#pragma unroll
  for (int i = 0; i < 8; ++i) {
    int r = row0 + ty * 8 + i;
    float ps = 0.f, pd = 0.f;
#pragma unroll
    for (int j = 0; j < TN; ++j) {
      ps = fmaf(acc[i][j], avs[j], ps);
      pd = fmaf(acc[i][j], avd[j], pd);
    }
    if (BN == 128) {
#pragma unroll
      for (int off = 1; off < 8; off <<= 1) {
        ps += __shfl_xor(ps, off);
        pd += __shfl_xor(pd, off);
      }
      if ((tx & 7) == 0 && r < M) { asrc[r * H + head] = ps; adst[r * H + head] = pd; }
    } else {
#pragma unroll
      for (int off = 1; off < 16; off <<= 1) {
        ps += __shfl_xor(ps, off);
        pd += __shfl_xor(pd, off);
      }
      if (tx == 0 && r < M) { asrc[r] = ps; adst[r] = pd; }
    }
    if (r < M) {
      __half tmp[TN];
#pragma unroll
      for (int j = 0; j < TN; ++j) tmp[j] = __float2half_rn(acc[i][j]);
      if (TN == 8)
        *reinterpret_cast<uint4*>(Tout + (size_t)r * Ncol + col0 + tx * TN) =
            *reinterpret_cast<uint4*>(tmp);
      else
        *reinterpret_cast<uint2*>(Tout + (size_t)r * Ncol + col0 + tx * TN) =
            *reinterpret_cast<uint2*>(tmp);
    }
  }
}

// Lane-parallel edge weights: thread per (CSR slot, head).
// w[j*4+h] = exp(lrelu(asrc[s,h] + adst[d,h])). Fully coalesced.
__global__ __launch_bounds__(256) void edge_weights_h4(
    const int* __restrict__ esrc, const int* __restrict__ edst,
    const float* __restrict__ asrc, const float* __restrict__ adst,
    float* __restrict__ w, int ET) {
  int t = blockIdx.x * 256 + threadIdx.x;
  if (t >= ET * 4) return;
  int j = t >> 2, h = t & 3;
  int s = esrc[j], d = edst[j];
  float e = asrc[s * 4 + h] + adst[d * 4 + h];
  e = fmaxf(e, 0.2f * e);  // leaky-relu
  w[t] = __expf(e);
}

__global__ __launch_bounds__(256) void edge_weights_h1(
    const int* __restrict__ esrc, const int* __restrict__ edst,
    const float* __restrict__ asrc, const float* __restrict__ adst,
    float* __restrict__ w, int ET) {
  int j = blockIdx.x * 256 + threadIdx.x;
  if (j >= ET) return;
  float e = asrc[esrc[j]] + adst[edst[j]];
  e = fmaxf(e, 0.2f * e);
  w[j] = __expf(e);
}

// H=4 aggregate: block per dst, wave = head, 4 groups of 16 lanes; group g
// owns edges j%4==g. Inner loop: esrc + w loads (broadcast), uint2 fp16
// gather, 4 cvt+fma, den fma. No LDS, no barriers, no exp in loop.
template <bool ELU>
__global__ __launch_bounds__(256) void aggregate_h4(
    const __half* __restrict__ T16, const int* __restrict__ row_off,
    const int* __restrict__ esrc, const float* __restrict__ w,
    const float* __restrict__ bias, float* __restrict__ out, int N) {
  int dst = blockIdx.x;
  int t = threadIdx.x;
  int h = t >> 6, lane = t & 63;
  int g = lane >> 4, l = lane & 15;
  int r0 = row_off[dst], r1 = row_off[dst + 1];
  const char* tbase = reinterpret_cast<const char*>(T16);
  uint coff = (uint)(h * 64 + l * 4) * 2;  // channel byte offset within row
  float den = 0.f, ax = 0.f, ay = 0.f, az = 0.f, aw = 0.f;
#pragma unroll 2
  for (int j = r0 + g; j < r1; j += 4) {
    int sj = esrc[j];                 // broadcast within group
    float wj = w[(j << 2) + h];       // broadcast within group
    den += wj;
    uint2 raw = *reinterpret_cast<const uint2*>(tbase + (((uint)sj << 9) + coff));
    __half2 p0 = *reinterpret_cast<__half2*>(&raw.x);
    __half2 p1 = *reinterpret_cast<__half2*>(&raw.y);
    float2 f0 = __half22float2(p0);
    float2 f1 = __half22float2(p1);
    ax = fmaf(wj, f0.x, ax);
    ay = fmaf(wj, f0.y, ay);
    az = fmaf(wj, f1.x, az);
    aw = fmaf(wj, f1.y, aw);
  }
  // cross-group reduce (groups differ in lane bits 4-5); den is
  // group-uniform so the same butterfly yields the full denominator.
#pragma unroll
  for (int off = 16; off < 64; off <<= 1) {
    ax += __shfl_xor(ax, off);
    ay += __shfl_xor(ay, off);
    az += __shfl_xor(az, off);
    aw += __shfl_xor(aw, off);
    den += __shfl_xor(den, off);
  }
  if (lane < 16) {
    int c0 = h * 64 + l * 4;
    float rd = 1.f / den;
    float4 v;
    v.x = ax * rd + bias[c0 + 0];
    v.y = ay * rd + bias[c0 + 1];
    v.z = az * rd + bias[c0 + 2];
    v.w = aw * rd + bias[c0 + 3];
    if (ELU) {
      v.x = v.x > 0.f ? v.x : expm1f(v.x);
      v.y = v.y > 0.f ? v.y : expm1f(v.y);
      v.z = v.z > 0.f ? v.z : expm1f(v.z);
      v.w = v.w > 0.f ? v.w : expm1f(v.w);
    }
    *reinterpret_cast<float4*>(&out[(size_t)dst * 256 + c0]) = v;
  }
}

// H=1 aggregate (layer 3): wave per dst, 4 dst/block, same structure.
__global__ __launch_bounds__(256) void aggregate_h1(
    const __half* __restrict__ T16, const int* __restrict__ row_off,
    const int* __restrict__ esrc, const float* __restrict__ w,
    const float* __restrict__ bias, float* __restrict__ out, int N) {
  int wv = threadIdx.x >> 6, lane = threadIdx.x & 63;
  int g = lane >> 4, l = lane & 15;
  int dst = blockIdx.x * 4 + wv;
  if (dst >= N) return;
  int r0 = row_off[dst], r1 = row_off[dst + 1];
  const char* tbase = reinterpret_cast<const char*>(T16);
  uint coff = (uint)(l * 4) * 2;
  float den = 0.f, ax = 0.f, ay = 0.f, az = 0.f, aw = 0.f;
#pragma unroll 2
  for (int j = r0 + g; j < r1; j += 4) {
    int sj = esrc[j];
    float wj = w[j];
    den += wj;
    uint2 raw = *reinterpret_cast<const uint2*>(tbase + (((uint)sj << 7) + coff));
    __half2 p0 = *reinterpret_cast<__half2*>(&raw.x);
    __half2 p1 = *reinterpret_cast<__half2*>(&raw.y);
    float2 f0 = __half22float2(p0);
    float2 f1 = __half22float2(p1);
    ax = fmaf(wj, f0.x, ax);
    ay = fmaf(wj, f0.y, ay);
    az = fmaf(wj, f1.x, az);
    aw = fmaf(wj, f1.y, aw);
  }
#pragma unroll
  for (int off = 16; off < 64; off <<= 1) {
    ax += __shfl_xor(ax, off);
    ay += __shfl_xor(ay, off);
    az += __shfl_xor(az, off);
    aw += __shfl_xor(aw, off);
    den += __shfl_xor(den, off);
  }
  if (lane < 16) {
    float rd = 1.f / den;
    float4 v;
    v.x = ax * rd + bias[l * 4 + 0];
    v.y = ay * rd + bias[l * 4 + 1];
    v.z = az * rd + bias[l * 4 + 2];
    v.w = aw * rd + bias[l * 4 + 3];
    *reinterpret_cast<float4*>(&out[(size_t)dst * 64 + l * 4]) = v;
  }
}

extern "C" void kernel_launch(void* const* d_in, const int* in_sizes, int n_in,
                              void* d_out, int out_size, void* d_ws, size_t ws_size,
                              hipStream_t stream) {
  const float* x   = (const float*)d_in[0];
  const int*   ei  = (const int*)d_in[1];
  const float* W1  = (const float*)d_in[2];
  const float* as1 = (const float*)d_in[3];
  const float* ad1 = (const float*)d_in[4];
  const float* b1  = (const float*)d_in[5];
  const float* W2  = (const float*)d_in[6];
  const float* as2 = (const float*)d_in[7];
  const float* ad2 = (const float*)d_in[8];
  const float* b2  = (const float*)d_in[9];
  const float* W3  = (const float*)d_in[10];
  const float* as3 = (const float*)d_in[11];
  const float* ad3 = (const float*)d_in[12];
  const float* b3  = (const float*)d_in[13];
  float* out = (float*)d_out;

  const int Fin = 128, H = 4, C = 64, HC = H * C;  // 256
  const int N = in_sizes[0] / Fin;
  const int E = in_sizes[1] / 2;
  const int ET = E + N;
  const int NB = (N + 1023) / 1024;

  // workspace layout (~106 MB)
  __half* T16   = (__half*)d_ws;                      // [N, 256] fp16
  __half* T16L3 = T16 + (size_t)N * HC;               // [N, 64] fp16
  float* F    = (float*)(T16L3 + (size_t)N * C);      // [N, 256]
  float* asrc = F + (size_t)N * HC;                   // [N, H]
  float* adst = asrc + (size_t)N * H;                 // [N, H]
  int* deg     = (int*)(adst + (size_t)N * H);
  int* row_off = deg + N;
  int* cursor  = row_off + (N + 1);
  int* bsum    = cursor + N;                          // [NB]
  int* bpre    = bsum + NB;                           // [NB]
  int* esrc    = bpre + NB;                           // [E + N]
  int* edst    = esrc + ET;                           // [E + N]
  float* wbuf  = (float*)(edst + ET);                 // [(E+N)*4]

  // ---- CSR by destination ----
  hipMemsetAsync(deg, 0, N * sizeof(int), stream);
  count_kernel<<<(ET + 255) / 256, 256, 0, stream>>>(ei, E, N, deg);
  deg_block_reduce<<<NB, 256, 0, stream>>>(deg, bsum, N);
  small_scan<<<1, 1024, 0, stream>>>(bsum, bpre, NB);
  scan_final<<<NB, 1024, 0, stream>>>(deg, bpre, row_off, cursor, N, ET);
  scatter_kernel<<<(ET + 255) / 256, 256, 0, stream>>>(ei, E, N, cursor, esrc, edst);

  dim3 g1((N + 127) / 128, HC / 128);
  int eb4 = (ET * 4 + 255) / 256, eb1 = (ET + 255) / 256;

  // ---- Layer 1: 128 -> 4x64 (concat) + ELU ----
  gemm_alpha<128><<<g1, 256, 0, stream>>>(x, W1, T16, as1, ad1, asrc, adst, N, Fin, HC);
  edge_weights_h4<<<eb4, 256, 0, stream>>>(esrc, edst, asrc, adst, wbuf, ET);
  aggregate_h4<true><<<N, 256, 0, stream>>>(T16, row_off, esrc, wbuf, b1, F, N);

  // ---- Layer 2: 256 -> 4x64 (concat) + ELU ----
  gemm_alpha<128><<<g1, 256, 0, stream>>>(F, W2, T16, as2, ad2, asrc, adst, N, HC, HC);
  edge_weights_h4<<<eb4, 256, 0, stream>>>(esrc, edst, asrc, adst, wbuf, ET);
  aggregate_h4<true><<<N, 256, 0, stream>>>(T16, row_off, esrc, wbuf, b2, F, N);

  // ---- Layer 3: 256 -> 1x64 (mean over 1 head == identity) ----
  gemm_alpha<64><<<dim3((N + 127) / 128, 1), 256, 0, stream>>>(
      F, W3, T16L3, as3, ad3, asrc, adst, N, HC, C);
  edge_weights_h1<<<eb1, 256, 0, stream>>>(esrc, edst, asrc, adst, wbuf, ET);
  aggregate_h1<<<(N + 3) / 4, 256, 0, stream>>>(T16L3, row_off, esrc, wbuf, b3, out, N);
}

// Round 8
// 367.161 us; speedup vs baseline: 1.4434x; 1.4434x over previous
//
#include <hip/hip_runtime.h>
#include <hip/hip_fp16.h>
#include <cstdint>

// ---------------------------------------------------------------------------
// 3-layer GAT (PyG GATConv semantics) on MI355X.
//   CSR by dst -> per layer: fp16 MFMA GEMM (fp32 acc) + fused fp32 alpha
//   epilogue -> lane-parallel edge weights -> wave-per-dst aggregate
//   (one wave reads the full 512B feature row; no shuffles/LDS in loop).
// Feature path fp16; logits/softmax/accumulation fp32.
// ---------------------------------------------------------------------------

typedef _Float16 f16;
typedef _Float16 f16x8 __attribute__((ext_vector_type(8)));
typedef float f32x4 __attribute__((ext_vector_type(4)));

__global__ __launch_bounds__(256) void count_kernel(const int* __restrict__ ei,
                                                    int E, int N,
                                                    int* __restrict__ deg) {
  int g = blockIdx.x * 256 + threadIdx.x;
  if (g >= E + N) return;
  int dst = (g < E) ? ei[E + g] : (g - E);
  atomicAdd(&deg[dst], 1);
}

__global__ __launch_bounds__(256) void deg_block_reduce(const int* __restrict__ deg,
                                                        int* __restrict__ bsum, int N) {
  __shared__ int red[4];
  int b = blockIdx.x;
  int v = 0;
#pragma unroll
  for (int s = 0; s < 4; ++s) {
    int idx = b * 1024 + s * 256 + threadIdx.x;
    if (idx < N) v += deg[idx];
  }
  for (int off = 32; off; off >>= 1) v += __shfl_down(v, off);
  if ((threadIdx.x & 63) == 0) red[threadIdx.x >> 6] = v;
  __syncthreads();
  if (threadIdx.x == 0) bsum[b] = red[0] + red[1] + red[2] + red[3];
}

__global__ __launch_bounds__(1024) void small_scan(const int* __restrict__ bsum,
                                                   int* __restrict__ bpre, int NB) {
  __shared__ int buf[1024];
  int v = (threadIdx.x < NB) ? bsum[threadIdx.x] : 0;
  buf[threadIdx.x] = v;
  __syncthreads();
  for (int off = 1; off < 1024; off <<= 1) {
    int tv = (threadIdx.x >= off) ? buf[threadIdx.x - off] : 0;
    __syncthreads();
    buf[threadIdx.x] += tv;
    __syncthreads();
  }
  if (threadIdx.x < NB) bpre[threadIdx.x] = buf[threadIdx.x] - v;
}

__global__ __launch_bounds__(1024) void scan_final(const int* __restrict__ deg,
                                                   const int* __restrict__ bpre,
                                                   int* __restrict__ row_off,
                                                   int* __restrict__ cursor,
                                                   int N, int total) {
  __shared__ int buf[1024];
  int b = blockIdx.x;
  int i = b * 1024 + threadIdx.x;
  int v = (i < N) ? deg[i] : 0;
  buf[threadIdx.x] = v;
  __syncthreads();
  for (int off = 1; off < 1024; off <<= 1) {
    int tv = (threadIdx.x >= off) ? buf[threadIdx.x - off] : 0;
    __syncthreads();
    buf[threadIdx.x] += tv;
    __syncthreads();
  }
  if (i < N) {
    int ro = bpre[b] + buf[threadIdx.x] - v;
    row_off[i] = ro;
    cursor[i] = ro;
  }
  if (i == 0) row_off[N] = total;
}

__global__ __launch_bounds__(256) void scatter_kernel(const int* __restrict__ ei,
                                                      int E, int N,
                                                      int* __restrict__ cursor,
                                                      int* __restrict__ esrc,
                                                      int* __restrict__ edst) {
  int g = blockIdx.x * 256 + threadIdx.x;
  if (g >= E + N) return;
  int src, dst;
  if (g < E) { src = ei[g]; dst = ei[E + g]; }
  else       { src = g - E; dst = src; }
  int pos = atomicAdd(&cursor[dst], 1);
  esrc[pos] = src;
  edst[pos] = dst;
}

// fp32 -> fp16 cast, 4 elems/thread (n multiple of 4).
__global__ __launch_bounds__(256) void convert_x(const float* __restrict__ x,
                                                 f16* __restrict__ xh, int n) {
  int i = (blockIdx.x * 256 + threadIdx.x) * 4;
  if (i >= n) return;
  float4 v = *reinterpret_cast<const float4*>(&x[i]);
  f16 o[4] = {(f16)v.x, (f16)v.y, (f16)v.z, (f16)v.w};
  *reinterpret_cast<uint2*>(&xh[i]) = *reinterpret_cast<uint2*>(o);
}

// W [K,Ncol] fp32 -> Wt [Ncol,K] fp16 (transpose; coalesced reads).
__global__ __launch_bounds__(256) void convert_wt(const float* __restrict__ W,
                                                  f16* __restrict__ Wt,
                                                  int K, int Ncol) {
  int t = blockIdx.x * 256 + threadIdx.x;
  if (t >= K * Ncol) return;
  int n = t % Ncol, k = t / Ncol;
  Wt[(size_t)n * K + k] = (f16)W[t];
}

// MFMA fp16 GEMM  T = A@B  with fused fp32 alpha epilogue; T written fp16.
// Block: 256 thr (4 waves), tile 128 x BN, BK=32. Wave wv owns rows
// [wv*32, wv*32+32). mfma_f32_16x16x32_f16 fragments:
//   A: row=lane&15, k=(lane>>4)*8+i (8 contiguous k)
//   B: col=lane&15, k=(lane>>4)*8+i  (staged from Wt[N][K], contiguous)
//   C/D: col=lane&15, row=(lane>>4)*4+reg
template <int BN>
__global__ __launch_bounds__(256) void mfma_gemm_alpha(
    const f16* __restrict__ A,    // [M,K] fp16
    const f16* __restrict__ Bt,   // [Ncol,K] fp16 (W transposed)
    f16* __restrict__ Tout,       // [M,Ncol] fp16
    const float* __restrict__ avec_src, const float* __restrict__ avec_dst,
    float* __restrict__ asrc, float* __restrict__ adst,
    int M, int K, int Ncol) {
  constexpr int CF = BN / 16;  // col frags per wave
  constexpr int HL = BN / 64;  // heads per block
  __shared__ f16 As[128][40];  // pad 40: 16B-aligned rows, 2-way bank (free)
  __shared__ f16 Bs[BN][40];
  int tid = threadIdx.x;
  int wv = tid >> 6, lane = tid & 63;
  int lrow = lane & 15, lkb = lane >> 4;
  int row0 = blockIdx.x * 128, col0 = blockIdx.y * BN;

  f32x4 acc[2][CF];
#pragma unroll
  for (int rf = 0; rf < 2; ++rf)
#pragma unroll
    for (int cf = 0; cf < CF; ++cf) acc[rf][cf] = (f32x4){0.f, 0.f, 0.f, 0.f};

  for (int kk = 0; kk < K; kk += 32) {
#pragma unroll
    for (int q = 0; q < 2; ++q) {  // A: 512 slots of 8 f16
      int slot = tid + q * 256;
      int r = slot >> 2, ko = (slot & 3) << 3;
      int gr = min(row0 + r, M - 1);
      *reinterpret_cast<f16x8*>(&As[r][ko]) =
          *reinterpret_cast<const f16x8*>(&A[(size_t)gr * K + kk + ko]);
    }
#pragma unroll
    for (int q = 0; q < BN / 64; ++q) {  // Bt: BN*4 slots
      int slot = tid + q * 256;
      int c = slot >> 2, ko = (slot & 3) << 3;
      *reinterpret_cast<f16x8*>(&Bs[c][ko]) =
          *reinterpret_cast<const f16x8*>(&Bt[(size_t)(col0 + c) * K + kk + ko]);
    }
    __syncthreads();
    f16x8 af[2], bf[CF];
#pragma unroll
    for (int rf = 0; rf < 2; ++rf)
      af[rf] = *reinterpret_cast<f16x8*>(&As[wv * 32 + rf * 16 + lrow][lkb * 8]);
#pragma unroll
    for (int cf = 0; cf < CF; ++cf)
      bf[cf] = *reinterpret_cast<f16x8*>(&Bs[cf * 16 + lrow][lkb * 8]);
#pragma unroll
    for (int rf = 0; rf < 2; ++rf)
#pragma unroll
      for (int cf = 0; cf < CF; ++cf)
        acc[rf][cf] = __builtin_amdgcn_mfma_f32_16x16x32_f16(af[rf], bf[cf],
                                                             acc[rf][cf], 0, 0, 0);
    __syncthreads();
  }

  // ---- alpha vectors: lane's channel within head = q*16 + lrow ----
  int Hh = Ncol >> 6;
  float avs[HL][4], avd[HL][4];
#pragma unroll
  for (int hl = 0; hl < HL; ++hl) {
    int hg = (col0 >> 6) + hl;
#pragma unroll
    for (int q = 0; q < 4; ++q) {
      avs[hl][q] = avec_src[hg * 64 + q * 16 + lrow];
      avd[hl][q] = avec_dst[hg * 64 + q * 16 + lrow];
    }
  }

#pragma unroll
  for (int rf = 0; rf < 2; ++rf) {
#pragma unroll
    for (int hl = 0; hl < HL; ++hl) {
      int hg = (col0 >> 6) + hl;
#pragma unroll
      for (int r = 0; r < 4; ++r) {
        float ps = 0.f, pd = 0.f;
#pragma unroll
        for (int q = 0; q < 4; ++q) {
          float v = acc[rf][hl * 4 + q][r];
          ps = fmaf(v, avs[hl][q], ps);
          pd = fmaf(v, avd[hl][q], pd);
        }
#pragma unroll
        for (int off = 1; off < 16; off <<= 1) {
          ps += __shfl_xor(ps, off);
          pd += __shfl_xor(pd, off);
        }
        int row = row0 + wv * 32 + rf * 16 + lkb * 4 + r;
        if (lrow == 0 && row < M) {
          asrc[row * Hh + hg] = ps;
          adst[row * Hh + hg] = pd;
        }
      }
    }
    // T16 stores: per reg r, lane stores col cf*16+lrow of its row.
#pragma unroll
    for (int r = 0; r < 4; ++r) {
      int row = row0 + wv * 32 + rf * 16 + lkb * 4 + r;
      if (row < M) {
#pragma unroll
        for (int cf = 0; cf < CF; ++cf)
          Tout[(size_t)row * Ncol + col0 + cf * 16 + lrow] = (f16)acc[rf][cf][r];
      }
    }
  }
}

// Lane-parallel edge weights (no max-shift: logits ~N(0,2), fp32-safe).
__global__ __launch_bounds__(256) void edge_weights_h4(
    const int* __restrict__ esrc, const int* __restrict__ edst,
    const float* __restrict__ asrc, const float* __restrict__ adst,
    float* __restrict__ w, int ET) {
  int t = blockIdx.x * 256 + threadIdx.x;
  if (t >= ET * 4) return;
  int j = t >> 2, h = t & 3;
  float e = asrc[esrc[j] * 4 + h] + adst[edst[j] * 4 + h];
  e = fmaxf(e, 0.2f * e);
  w[t] = __expf(e);
}

__global__ __launch_bounds__(256) void edge_weights_h1(
    const int* __restrict__ esrc, const int* __restrict__ edst,
    const float* __restrict__ asrc, const float* __restrict__ adst,
    float* __restrict__ w, int ET) {
  int j = blockIdx.x * 256 + threadIdx.x;
  if (j >= ET) return;
  float e = asrc[esrc[j]] + adst[edst[j]];
  e = fmaxf(e, 0.2f * e);
  w[j] = __expf(e);
}

// H=4 aggregate: ONE wave per dst covers all 4 heads. lane = head*16 + l;
// per edge the 64 lanes read the full 512B row in one uint2 load. den is
// per-16-lane-group uniform; each lane exclusively owns 4 channels -> no
// reductions at all. Output written fp16 (feeds next GEMM).
template <bool ELU>
__global__ __launch_bounds__(256) void aggregate_h4(
    const f16* __restrict__ T16, const int* __restrict__ row_off,
    const int* __restrict__ esrc, const float* __restrict__ w,
    const float* __restrict__ bias, f16* __restrict__ outF, int N) {
  int wv = threadIdx.x >> 6, lane = threadIdx.x & 63;
  int dst = blockIdx.x * 4 + wv;
  if (dst >= N) return;
  int head = lane >> 4;
  int r0 = row_off[dst], r1 = row_off[dst + 1];
  const char* tbase = reinterpret_cast<const char*>(T16);
  uint loff = (uint)lane * 8;  // byte offset within 512B row
  float den = 0.f, ax = 0.f, ay = 0.f, az = 0.f, aw = 0.f;
#pragma unroll 2
  for (int j = r0; j < r1; ++j) {
    int sj = esrc[j];             // wave-uniform broadcast
    float wj = w[(j << 2) + head];
    den += wj;
    uint2 raw = *reinterpret_cast<const uint2*>(tbase + (((uint)sj << 9) + loff));
    __half2 p0 = *reinterpret_cast<__half2*>(&raw.x);
    __half2 p1 = *reinterpret_cast<__half2*>(&raw.y);
    float2 f0 = __half22float2(p0);
    float2 f1 = __half22float2(p1);
    ax = fmaf(wj, f0.x, ax);
    ay = fmaf(wj, f0.y, ay);
    az = fmaf(wj, f1.x, az);
    aw = fmaf(wj, f1.y, aw);
  }
  float rd = 1.f / den;
  float4 bv = *reinterpret_cast<const float4*>(&bias[lane << 2]);
  float vx = ax * rd + bv.x, vy = ay * rd + bv.y;
  float vz = az * rd + bv.z, vw = aw * rd + bv.w;
  if (ELU) {
    vx = vx > 0.f ? vx : expm1f(vx);
    vy = vy > 0.f ? vy : expm1f(vy);
    vz = vz > 0.f ? vz : expm1f(vz);
    vw = vw > 0.f ? vw : expm1f(vw);
  }
  f16 o[4] = {(f16)vx, (f16)vy, (f16)vz, (f16)vw};
  *reinterpret_cast<uint2*>(&outF[(size_t)dst * 256 + (lane << 2)]) =
      *reinterpret_cast<uint2*>(o);
}

// H=1 aggregate (layer 3): wave per dst, 4 groups x 16 lanes, group g owns
// edges j%4==g; fp32 output to d_out.
__global__ __launch_bounds__(256) void aggregate_h1(
    const f16* __restrict__ T16, const int* __restrict__ row_off,
    const int* __restrict__ esrc, const float* __restrict__ w,
    const float* __restrict__ bias, float* __restrict__ out, int N) {
  int wv = threadIdx.x >> 6, lane = threadIdx.x & 63;
  int g = lane >> 4, l = lane & 15;
  int dst = blockIdx.x * 4 + wv;
  if (dst >= N) return;
  int r0 = row_off[dst], r1 = row_off[dst + 1];
  const char* tbase = reinterpret_cast<const char*>(T16);
  uint coff = (uint)l * 8;
  float den = 0.f, ax = 0.f, ay = 0.f, az = 0.f, aw = 0.f;
#pragma unroll 2
  for (int j = r0 + g; j < r1; j += 4) {
    int sj = esrc[j];
    float wj = w[j];
    den += wj;
    uint2 raw = *reinterpret_cast<const uint2*>(tbase + (((uint)sj << 7) + coff));
    __half2 p0 = *reinterpret_cast<__half2*>(&raw.x);
    __half2 p1 = *reinterpret_cast<__half2*>(&raw.y);
    float2 f0 = __half22float2(p0);
    float2 f1 = __half22float2(p1);
    ax = fmaf(wj, f0.x, ax);
    ay = fmaf(wj, f0.y, ay);
    az = fmaf(wj, f1.x, az);
    aw = fmaf(wj, f1.y, aw);
  }
#pragma unroll
  for (int off = 16; off < 64; off <<= 1) {
    ax += __shfl_xor(ax, off);
    ay += __shfl_xor(ay, off);
    az += __shfl_xor(az, off);
    aw += __shfl_xor(aw, off);
    den += __shfl_xor(den, off);
  }
  if (lane < 16) {
    float rd = 1.f / den;
    float4 v;
    v.x = ax * rd + bias[l * 4 + 0];
    v.y = ay * rd + bias[l * 4 + 1];
    v.z = az * rd + bias[l * 4 + 2];
    v.w = aw * rd + bias[l * 4 + 3];
    *reinterpret_cast<float4*>(&out[(size_t)dst * 64 + l * 4]) = v;
  }
}

extern "C" void kernel_launch(void* const* d_in, const int* in_sizes, int n_in,
                              void* d_out, int out_size, void* d_ws, size_t ws_size,
                              hipStream_t stream) {
  const float* x   = (const float*)d_in[0];
  const int*   ei  = (const int*)d_in[1];
  const float* W1  = (const float*)d_in[2];
  const float* as1 = (const float*)d_in[3];
  const float* ad1 = (const float*)d_in[4];
  const float* b1  = (const float*)d_in[5];
  const float* W2  = (const float*)d_in[6];
  const float* as2 = (const float*)d_in[7];
  const float* ad2 = (const float*)d_in[8];
  const float* b2  = (const float*)d_in[9];
  const float* W3  = (const float*)d_in[10];
  const float* as3 = (const float*)d_in[11];
  const float* ad3 = (const float*)d_in[12];
  const float* b3  = (const float*)d_in[13];
  float* out = (float*)d_out;

  const int Fin = 128, H = 4, C = 64, HC = H * C;  // 256
  const int N = in_sizes[0] / Fin;
  const int E = in_sizes[1] / 2;
  const int ET = E + N;
  const int NB = (N + 1023) / 1024;

  // workspace layout (~93 MB)
  f16* xh    = (f16*)d_ws;                       // [N,128]
  f16* T16   = xh + (size_t)N * Fin;             // [N,256]
  f16* F16   = T16 + (size_t)N * HC;             // [N,256]
  f16* T16L3 = F16 + (size_t)N * HC;             // [N,64]
  f16* Wt1   = T16L3 + (size_t)N * C;            // [256,128]
  f16* Wt2   = Wt1 + HC * Fin;                   // [256,256]
  f16* Wt3   = Wt2 + HC * HC;                    // [64,256]
  float* asrc = (float*)(Wt3 + C * HC);          // [N,H]
  float* adst = asrc + (size_t)N * H;            // [N,H]
  float* wbuf = adst + (size_t)N * H;            // [(E+N)*4]
  int* deg     = (int*)(wbuf + (size_t)ET * 4);
  int* row_off = deg + N;
  int* cursor  = row_off + (N + 1);
  int* bsum    = cursor + N;
  int* bpre    = bsum + NB;
  int* esrc    = bpre + NB;                      // [E+N]
  int* edst    = esrc + ET;                      // [E+N]

  // ---- CSR by destination ----
  hipMemsetAsync(deg, 0, N * sizeof(int), stream);
  count_kernel<<<(ET + 255) / 256, 256, 0, stream>>>(ei, E, N, deg);
  deg_block_reduce<<<NB, 256, 0, stream>>>(deg, bsum, N);
  small_scan<<<1, 1024, 0, stream>>>(bsum, bpre, NB);
  scan_final<<<NB, 1024, 0, stream>>>(deg, bpre, row_off, cursor, N, ET);
  scatter_kernel<<<(ET + 255) / 256, 256, 0, stream>>>(ei, E, N, cursor, esrc, edst);

  // ---- fp16 conversions ----
  convert_x<<<(N * Fin / 4 + 255) / 256, 256, 0, stream>>>(x, xh, N * Fin);
  convert_wt<<<(Fin * HC + 255) / 256, 256, 0, stream>>>(W1, Wt1, Fin, HC);
  convert_wt<<<(HC * HC + 255) / 256, 256, 0, stream>>>(W2, Wt2, HC, HC);
  convert_wt<<<(HC * C + 255) / 256, 256, 0, stream>>>(W3, Wt3, HC, C);

  int gx = (N + 127) / 128;
  int eb4 = (ET * 4 + 255) / 256, eb1 = (ET + 255) / 256;
  int ab = (N + 3) / 4;

  // ---- Layer 1: 128 -> 4x64 (concat) + ELU ----
  mfma_gemm_alpha<128><<<dim3(gx, 2), 256, 0, stream>>>(
      xh, Wt1, T16, as1, ad1, asrc, adst, N, Fin, HC);
  edge_weights_h4<<<eb4, 256, 0, stream>>>(esrc, edst, asrc, adst, wbuf, ET);
  aggregate_h4<true><<<ab, 256, 0, stream>>>(T16, row_off, esrc, wbuf, b1, F16, N);

  // ---- Layer 2: 256 -> 4x64 (concat) + ELU ----
  mfma_gemm_alpha<128><<<dim3(gx, 2), 256, 0, stream>>>(
      F16, Wt2, T16, as2, ad2, asrc, adst, N, HC, HC);
  edge_weights_h4<<<eb4, 256, 0, stream>>>(esrc, edst, asrc, adst, wbuf, ET);
  aggregate_h4<true><<<ab, 256, 0, stream>>>(T16, row_off, esrc, wbuf, b2, F16, N);

  // ---- Layer 3: 256 -> 1x64 ----
  mfma_gemm_alpha<64><<<dim3(gx, 1), 256, 0, stream>>>(
      F16, Wt3, T16L3, as3, ad3, asrc, adst, N, HC, C);
  edge_weights_h1<<<eb1, 256, 0, stream>>>(esrc, edst, asrc, adst, wbuf, ET);
  aggregate_h1<<<ab, 256, 0, stream>>>(T16L3, row_off, esrc, wbuf, b3, out, N);
}